// Round 6
// baseline (431.491 us; speedup 1.0000x reference)
//
#include <hip/hip_runtime.h>
#include <math.h>

#define Dd 128
#define Tt 1024
#define Kk 2048
#define Nn 65536
#define DT 131072  // Dd*Tt

typedef __attribute__((ext_vector_type(8))) short short8;
typedef __attribute__((ext_vector_type(4))) float float4v;

__device__ __forceinline__ unsigned umin_(unsigned a, unsigned b) { return a < b ? a : b; }
__device__ __forceinline__ unsigned umax_(unsigned a, unsigned b) { return a > b ? a : b; }

// ws layout (bytes):
//   cbh     @ 0        : ushort[262144] = 524288   (bf16 hi plane of codebook, [k][d])
//   e2f     @ 524288   : float[2048]    = 8192     (np-replica fp32 ||e||^2)
//   Arow    @ 532480   : float[65536]   = 262144   (np-replica fp32 ||x||^2, by score_kernel)
//   idxbuf  @ 794624   : int[65536]     = 262144
//   counts  @ 1056768  : int[2048]      = 8192
//   part    @ 1064960  : double[512]    = 4096
//   cand_g  @ 1069056  : ushort[65536*16] = 2097152
//   candcnt @ 3166208  : int[65536]     = 262144
// total 3428352 B (~3.43 MB)

// Codebook-only setup: bf16-hi plane + zero histogram (blocks 0..1023),
// np-replica fp32 ||e||^2 (blocks 1024..1031; 8-acc pairwise order, __f*_rn
// blocks FMA contraction so each square rounds like numpy's flat*flat).
__global__ __launch_bounds__(256)
void setup_kernel(const float* __restrict__ cb, ushort* __restrict__ cbh,
                  float* __restrict__ e2f, int* __restrict__ counts) {
  const int bid = blockIdx.x, tid = threadIdx.x;
  if (bid < 1024) {
    const int g = bid * 256 + tid;                // 262144 codebook elems
    const unsigned u = __float_as_uint(cb[g]);
    cbh[g] = (ushort)((u + 0x7FFFu + ((u >> 16) & 1u)) >> 16);  // RNE bf16
    if (g < Kk) counts[g] = 0;
  } else {
    const int k = (bid - 1024) * 256 + tid;       // 2048 codes
    const float* p = cb + (size_t)k * Dd;
    float r[8];
    #pragma unroll
    for (int j = 0; j < 8; ++j) r[j] = __fmul_rn(p[j], p[j]);
    for (int i = 1; i < 16; ++i) {
      #pragma unroll
      for (int j = 0; j < 8; ++j) {
        const float v = p[8 * i + j];
        r[j] = __fadd_rn(r[j], __fmul_rn(v, v));
      }
    }
    e2f[k] = __fadd_rn(__fadd_rn(__fadd_rn(r[0], r[1]), __fadd_rn(r[2], r[3])),
                       __fadd_rn(__fadd_rn(r[4], r[5]), __fadd_rn(r[6], r[7])));
  }
}

// Single-sweep bf16 MFMA scoring with per-thread top-3 packed keys.
// key = (mono(score) & ~0x7FF) | k  — u32-monotone in score, ties -> low k.
// A-frags preloaded to registers (zs fp32 LDS transpose, also yields Arow).
// 64 rows/block, 32 chunks of 64 codes; wave tile 32x32 (4x 16x16x32 MFMA).
__global__ __launch_bounds__(256, 3)
void score_kernel(const float* __restrict__ z, const ushort* __restrict__ cbh,
                  const float* __restrict__ e2f, float* __restrict__ Arow,
                  ushort* __restrict__ cand_g, int* __restrict__ candcnt) {
  __shared__ char smem[32768];
  __shared__ float marg[64];
  __shared__ unsigned seedk[64];
  float* zs = (float*)smem;                      // [128][64] fp32 (staging phase)
  ushort* eh = (ushort*)smem;                    // [8192] swizzled (sweep phase)
  unsigned* sred = (unsigned*)(smem + 16384);    // [64][32] (post-sweep)
  int* cnt = (int*)(smem + 24576);               // [64]
  ushort* candL = (ushort*)(smem + 24832);       // [64][16]
  const int tid = threadIdx.x;
  const int n0 = blockIdx.x * 64;                // 1024 blocks
  const int bb = n0 >> 10, t0 = n0 & 1023;
  const float* zb = z + (size_t)bb * DT + t0;
  // ---- stage z fp32 into zs[d][row] (coalesced read, conflict-free write) ----
  {
    const int i = tid & 63, dg = tid >> 6;
    #pragma unroll
    for (int j = 0; j < 32; ++j) {
      const int d = dg + 4 * j;
      zs[d * 64 + i] = zb[d * Tt + i];
    }
  }
  __syncthreads();
  const int lane = tid & 63, wv = tid >> 6;
  const int col = lane & 15, quad = lane >> 4;
  const int R0 = (wv >> 1) * 32, C0 = (wv & 1) * 32;
  // ---- A-frag preload (bf16 RNE) into registers ----
  short8 ahf[2][4];
  #pragma unroll
  for (int rt = 0; rt < 2; ++rt) {
    const int row = R0 + rt * 16 + col;
    #pragma unroll
    for (int ks = 0; ks < 4; ++ks) {
      const int d0 = (ks * 4 + quad) * 8;
      short8 t;
      #pragma unroll
      for (int j = 0; j < 8; ++j) {
        const unsigned u = __float_as_uint(zs[(d0 + j) * 64 + row]);
        t[j] = (short)((u + 0x7FFFu + ((u >> 16) & 1u)) >> 16);
      }
      ahf[rt][ks] = t;
    }
  }
  // ---- Arow (np-replica pairwise fp32) + margin ----
  if (tid < 64) {
    float r8[8];
    #pragma unroll
    for (int j = 0; j < 8; ++j) {
      const float v = zs[j * 64 + tid];
      r8[j] = __fmul_rn(v, v);
    }
    for (int i = 1; i < 16; ++i) {
      #pragma unroll
      for (int j = 0; j < 8; ++j) {
        const float v = zs[(8 * i + j) * 64 + tid];
        r8[j] = __fadd_rn(r8[j], __fmul_rn(v, v));
      }
    }
    const float A = __fadd_rn(__fadd_rn(__fadd_rn(r8[0], r8[1]), __fadd_rn(r8[2], r8[3])),
                              __fadd_rn(__fadd_rn(r8[4], r8[5]), __fadd_rn(r8[6], r8[7])));
    Arow[n0 + tid] = A;
    marg[tid] = 8.7e-5f * sqrtf(A) + 1.5e-4f;   // R5-validated + key-trunc slack
  }
  __syncthreads();                               // zs dead; eh region writable
  // ---- sweep: single pass, reg-prefetched staging, top-3 keys ----
  uint4 rcur[4];
  #pragma unroll
  for (int sw = 0; sw < 4; ++sw) {               // preload chunk 0
    const int s = sw * 256 + tid;
    const int c = s >> 4, kb = (s & 15) ^ (c & 15);
    rcur[sw] = *(const uint4*)(cbh + (((size_t)c) << 7) + (kb << 3));
  }
  unsigned t1[8], t2[8], t3[8];
  #pragma unroll
  for (int sl = 0; sl < 8; ++sl) { t1[sl] = 0xFFFFFFFFu; t2[sl] = 0xFFFFFFFFu; t3[sl] = 0xFFFFFFFFu; }
  const float4v vzero = {0.f, 0.f, 0.f, 0.f};
  for (int ch = 0; ch < 32; ++ch) {
    if (ch) __syncthreads();                     // prev chunk's readers done
    #pragma unroll
    for (int sw = 0; sw < 4; ++sw)
      ((uint4*)eh)[sw * 256 + tid] = rcur[sw];   // ds_write_b128
    if (ch + 1 < 32) {
      #pragma unroll
      for (int sw = 0; sw < 4; ++sw) {           // prefetch next chunk
        const int s = sw * 256 + tid;
        const int c = s >> 4, kb = (s & 15) ^ (c & 15);
        rcur[sw] = *(const uint4*)(cbh + (((size_t)((ch + 1) * 64 + c)) << 7) + (kb << 3));
      }
    }
    __syncthreads();                             // eh ready
    float4v acc[2][2];
    #pragma unroll
    for (int rt = 0; rt < 2; ++rt)
      #pragma unroll
      for (int ct = 0; ct < 2; ++ct) acc[rt][ct] = vzero;
    #pragma unroll
    for (int ks = 0; ks < 4; ++ks) {
      const int kb = ks * 4 + quad;
      short8 bh[2];
      #pragma unroll
      for (int ct = 0; ct < 2; ++ct)
        bh[ct] = *(const short8*)&eh[((C0 + ct * 16 + col) << 7) + ((kb ^ col) << 3)];
      #pragma unroll
      for (int rt = 0; rt < 2; ++rt)
        #pragma unroll
        for (int ct = 0; ct < 2; ++ct)
          acc[rt][ct] = __builtin_amdgcn_mfma_f32_16x16x32_bf16(ahf[rt][ks], bh[ct], acc[rt][ct], 0, 0, 0);
    }
    const int c0g = ch * 64;
    #pragma unroll
    for (int ct = 0; ct < 2; ++ct) {
      const int kg0 = c0g + C0 + ct * 16 + col;
      const float e2v = e2f[kg0];
      #pragma unroll
      for (int rt = 0; rt < 2; ++rt)
        #pragma unroll
        for (int r = 0; r < 4; ++r) {
          const float s = __builtin_fmaf(-2.0f, acc[rt][ct][r], e2v);
          const unsigned u = __float_as_uint(s);
          const unsigned mono = u ^ ((unsigned)(((int)u) >> 31) | 0x80000000u);
          const unsigned key = (mono & 0xFFFFF800u) | (unsigned)kg0;
          const int sl = rt * 4 + r;
          const unsigned m1 = umax_(t1[sl], key); t1[sl] = umin_(t1[sl], key);
          const unsigned m2 = umax_(t2[sl], m1);  t2[sl] = umin_(t2[sl], m1);
          t3[sl] = umin_(t3[sl], m2);
        }
    }
  }
  __syncthreads();
  // ---- row-global min (u32 keys) -> threshold key ----
  #pragma unroll
  for (int rt = 0; rt < 2; ++rt)
    #pragma unroll
    for (int r = 0; r < 4; ++r)
      sred[(R0 + rt * 16 + quad * 4 + r) * 32 + (wv & 1) * 16 + col] = t1[rt * 4 + r];
  if (tid < 64) cnt[tid] = 0;
  __syncthreads();
  if (tid < 64) {
    unsigned m = sred[tid * 32];
    for (int j = 1; j < 32; ++j) m = umin_(m, sred[tid * 32 + j]);
    const unsigned mt = m & 0xFFFFF800u;                 // trunc-down (conservative)
    const unsigned uu = (mt & 0x80000000u) ? (mt ^ 0x80000000u) : ~mt;
    const float tf = __uint_as_float(uu) + marg[tid];
    const unsigned u2 = __float_as_uint(tf);
    const unsigned mono2 = u2 ^ ((unsigned)(((int)u2) >> 31) | 0x80000000u);
    seedk[tid] = mono2 | 0x7FFu;                         // inclusive in trunc domain
  }
  __syncthreads();
  // ---- append qualifying candidates; flag unbounded threads ----
  #pragma unroll
  for (int rt = 0; rt < 2; ++rt)
    #pragma unroll
    for (int r = 0; r < 4; ++r) {
      const int sl = rt * 4 + r;
      const int row = R0 + rt * 16 + quad * 4 + r;
      const unsigned th = seedk[row];
      if (t1[sl] <= th) {
        const int pos = atomicAdd(&cnt[row], 1);
        if (pos < 16) candL[row * 16 + pos] = (ushort)(t1[sl] & 0x7FFu);
        if (t2[sl] <= th) {
          const int pos2 = atomicAdd(&cnt[row], 1);
          if (pos2 < 16) candL[row * 16 + pos2] = (ushort)(t2[sl] & 0x7FFu);
          if (t3[sl] <= th) atomicAdd(&cnt[row], 64);   // 4th qualifier unbounded -> fallback
        }
      }
    }
  __syncthreads();
  if (tid < 64) {
    const int n = n0 + tid;
    candcnt[n] = cnt[tid];
    uint4* dst = (uint4*)(cand_g + (size_t)n * 16);
    const uint4* src = (const uint4*)(candL + tid * 16);
    dst[0] = src[0];
    dst[1] = src[1];
  }
}

// Exact np-replica rescore (R2-verified formula) + f64 loss partials.
__global__ __launch_bounds__(256)
void rescore_kernel(const float* __restrict__ z, const float* __restrict__ cb,
                    const float* __restrict__ e2f, const float* __restrict__ Arow,
                    const ushort* __restrict__ cand_g, const int* __restrict__ candcnt,
                    int* __restrict__ idxbuf, int* __restrict__ counts,
                    float* __restrict__ out_idx, double* __restrict__ part) {
  const int tid = threadIdx.x;
  const int n = blockIdx.x * 256 + tid;           // 256 blocks
  const int c = candcnt[n];
  double sq = 0.0;
  if (c >= 1 && c <= 16) {                        // fallback handles the rest
    const int b = n >> 10, t = n & 1023;
    const float* zb = z + (size_t)b * DT + t;
    const float A = Arow[n];
    float best = 1e30f;
    int bk = Kk;
    for (int j = 0; j < c; ++j) {
      const int k = cand_g[(size_t)n * 16 + j];
      const float* e = cb + (size_t)k * Dd;
      double acc = 0.0;
      #pragma unroll 8
      for (int d = 0; d < 128; d += 4) {
        const float4 ev = *(const float4*)(e + d);
        acc += (double)zb[(d + 0) * Tt] * (double)ev.x;
        acc += (double)zb[(d + 1) * Tt] * (double)ev.y;
        acc += (double)zb[(d + 2) * Tt] * (double)ev.z;
        acc += (double)zb[(d + 3) * Tt] * (double)ev.w;
      }
      const float m32 = (float)acc;
      const float X = __fsub_rn(A, __fmul_rn(2.0f, m32));
      const float Dq = __fadd_rn(X, e2f[k]);
      if (Dq < best || (Dq == best && k < bk)) { best = Dq; bk = k; }
    }
    idxbuf[n] = bk;
    out_idx[n] = (float)bk;
    atomicAdd(&counts[bk], 1);
    const float* ew = cb + (size_t)bk * Dd;       // winner loss pass
    #pragma unroll 8
    for (int d = 0; d < 128; ++d) {
      const double dif = (double)zb[d * Tt] - (double)ew[d];
      sq += dif * dif;
    }
  }
  #pragma unroll
  for (int o = 32; o > 0; o >>= 1) sq += __shfl_down(sq, o, 64);
  __shared__ double w4[4];
  if ((tid & 63) == 0) w4[tid >> 6] = sq;
  __syncthreads();
  if (tid == 0) part[blockIdx.x] = w4[0] + w4[1] + w4[2] + w4[3];
}

// Fallback: full exact scan for flagged/overflowed rows (expected: ~60 rows).
__global__ __launch_bounds__(256)
void fallback_kernel(const float* __restrict__ z, const float* __restrict__ cb,
                     const float* __restrict__ e2f, const float* __restrict__ Arow,
                     const int* __restrict__ candcnt, int* __restrict__ idxbuf,
                     int* __restrict__ counts, float* __restrict__ out_idx,
                     double* __restrict__ part) {
  __shared__ int flags[256];
  __shared__ int nf;
  __shared__ float xrow[128];
  __shared__ float rs[256];
  __shared__ int rk[256];
  const int tid = threadIdx.x;
  const int nb = blockIdx.x * 256;                // 256 blocks
  if (tid == 0) { nf = 0; part[256 + blockIdx.x] = 0.0; }
  __syncthreads();
  const int c = candcnt[nb + tid];
  const int bad = (c < 1 || c > 16) ? 1 : 0;
  flags[tid] = bad;
  if (bad) atomicAdd(&nf, 1);
  __syncthreads();
  if (nf == 0) return;                            // fast path
  double bsum = 0.0;
  for (int rr = 0; rr < 256; ++rr) {
    if (!flags[rr]) continue;                     // block-uniform
    const int n = nb + rr;
    const int b = n >> 10, t = n & 1023;
    if (tid < 128) xrow[tid] = z[(size_t)b * DT + (size_t)tid * Tt + t];
    __syncthreads();
    const float A = Arow[n];
    float best = 1e30f;
    int bk = Kk;
    for (int kk = tid * 8; kk < tid * 8 + 8; ++kk) {
      const float* e = cb + (size_t)kk * Dd;
      double acc = 0.0;
      for (int d = 0; d < 128; d += 4) {
        const float4 ev = *(const float4*)(e + d);
        acc += (double)xrow[d + 0] * (double)ev.x;
        acc += (double)xrow[d + 1] * (double)ev.y;
        acc += (double)xrow[d + 2] * (double)ev.z;
        acc += (double)xrow[d + 3] * (double)ev.w;
      }
      const float m32 = (float)acc;
      const float Dq = __fadd_rn(__fsub_rn(A, __fmul_rn(2.0f, m32)), e2f[kk]);
      if (Dq < best || (Dq == best && kk < bk)) { best = Dq; bk = kk; }
    }
    rs[tid] = best;
    rk[tid] = bk;
    __syncthreads();
    for (int o = 128; o > 0; o >>= 1) {
      if (tid < o) {
        if (rs[tid + o] < rs[tid] || (rs[tid + o] == rs[tid] && rk[tid + o] < rk[tid])) {
          rs[tid] = rs[tid + o];
          rk[tid] = rk[tid + o];
        }
      }
      __syncthreads();
    }
    if (tid == 0) {
      const int w = rk[0];
      idxbuf[n] = w;
      out_idx[n] = (float)w;
      atomicAdd(&counts[w], 1);
      const float* ew = cb + (size_t)w * Dd;
      for (int d = 0; d < 128; ++d) {
        const double dif = (double)xrow[d] - (double)ew[d];
        bsum += dif * dif;
      }
    }
    __syncthreads();
  }
  if (tid == 0) part[256 + blockIdx.x] = bsum;
}

// Gather z_q via LDS transpose: coalesced cb-row reads -> coalesced t-writes.
__global__ __launch_bounds__(256)
void gather_kernel(const float* __restrict__ cb, const int* __restrict__ idxbuf,
                   float* __restrict__ out0) {
  __shared__ float ldsT[128 * 65];                // +1 row pad vs 64
  const int tid = threadIdx.x;
  const int n0 = blockIdx.x * 64;                 // 1024 blocks
  const int b = n0 >> 10, t0 = n0 & 1023;
  const int r = tid >> 2;                         // 0..63 row
  const int dseg = (tid & 3) * 32;
  const int k = idxbuf[n0 + r];
  const float* e = cb + (size_t)k * Dd + dseg;
  #pragma unroll
  for (int j = 0; j < 8; ++j) {
    const float4 v = *(const float4*)(e + j * 4); // coalesced 512B/row
    const int d = dseg + j * 4;
    ldsT[(d + 0) * 65 + r] = v.x;
    ldsT[(d + 1) * 65 + r] = v.y;
    ldsT[(d + 2) * 65 + r] = v.z;
    ldsT[(d + 3) * 65 + r] = v.w;
  }
  __syncthreads();
  float* ob = out0 + (size_t)b * DT + t0;
  const int i = tid & 63;
  const int dg = tid >> 6;
  #pragma unroll
  for (int j = 0; j < 32; ++j) {
    const int d = dg * 32 + j;
    ob[d * Tt + i] = ldsT[d * 65 + i];            // coalesced over i
  }
}

__global__ __launch_bounds__(256)
void finalize_kernel(const int* __restrict__ counts, const double* __restrict__ part,
                     float* __restrict__ out) {
  const int tid = threadIdx.x;
  __shared__ double red[256];
  double s = 0.0;
  for (int i = tid; i < 512; i += 256) s += part[i];
  red[tid] = s;
  __syncthreads();
  for (int o = 128; o > 0; o >>= 1) {
    if (tid < o) red[tid] += red[tid + o];
    __syncthreads();
  }
  const double loss = red[0];
  __syncthreads();
  double e = 0.0;
  for (int k = tid; k < 2048; k += 256) {
    const double p = (double)counts[k] / 65536.0;
    e += p * log(p + 1e-10);
  }
  red[tid] = e;
  __syncthreads();
  for (int o = 128; o > 0; o >>= 1) {
    if (tid < o) red[tid] += red[tid + o];
    __syncthreads();
  }
  if (tid == 0) {
    out[8388608] = (float)(0.25 * loss / 8388608.0);
    out[8388609] = (float)exp(-red[0]);
  }
}

extern "C" void kernel_launch(void* const* d_in, const int* in_sizes, int n_in,
                              void* d_out, int out_size, void* d_ws, size_t ws_size,
                              hipStream_t stream) {
  const float* z = (const float*)d_in[0];      // (B, D, T) fp32
  const float* cb = (const float*)d_in[1];     // (K, D) fp32
  float* out = (float*)d_out;                  // [z_q (8388608) | loss | perp | idx (65536)]
  char* ws = (char*)d_ws;
  ushort* cbh    = (ushort*)ws;
  float* e2f     = (float*)(ws + 524288);
  float* Arow    = (float*)(ws + 532480);
  int* idxbuf    = (int*)(ws + 794624);
  int* counts    = (int*)(ws + 1056768);
  double* part   = (double*)(ws + 1064960);
  ushort* cand_g = (ushort*)(ws + 1069056);
  int* candcnt   = (int*)(ws + 3166208);

  hipLaunchKernelGGL(setup_kernel,    dim3(1032), dim3(256), 0, stream, cb, cbh, e2f, counts);
  hipLaunchKernelGGL(score_kernel,    dim3(1024), dim3(256), 0, stream, z, cbh, e2f, Arow,
                     cand_g, candcnt);
  hipLaunchKernelGGL(rescore_kernel,  dim3(256),  dim3(256), 0, stream, z, cb, e2f, Arow,
                     cand_g, candcnt, idxbuf, counts, out + 8388610, part);
  hipLaunchKernelGGL(fallback_kernel, dim3(256),  dim3(256), 0, stream, z, cb, e2f, Arow,
                     candcnt, idxbuf, counts, out + 8388610, part);
  hipLaunchKernelGGL(gather_kernel,   dim3(1024), dim3(256), 0, stream, cb, idxbuf, out);
  hipLaunchKernelGGL(finalize_kernel, dim3(1),    dim3(256), 0, stream, counts, part, out);
}

// Round 7
// 335.060 us; speedup vs baseline: 1.2878x; 1.2878x over previous
//
#include <hip/hip_runtime.h>
#include <math.h>

#define Dd 128
#define Tt 1024
#define Kk 2048
#define Nn 65536
#define DT 131072  // Dd*Tt

typedef __attribute__((ext_vector_type(8))) short short8;
typedef __attribute__((ext_vector_type(4))) float float4v;

__device__ __forceinline__ unsigned umin_(unsigned a, unsigned b) { return a < b ? a : b; }
__device__ __forceinline__ unsigned umax_(unsigned a, unsigned b) { return a > b ? a : b; }

// async global->LDS, 16B per lane; lds dest must be wave-uniform base (+lane*16)
__device__ __forceinline__ void dma16(const void* g, void* l) {
  __builtin_amdgcn_global_load_lds(
      (const __attribute__((address_space(1))) unsigned int*)g,
      (__attribute__((address_space(3))) unsigned int*)l, 16, 0, 0);
}

// ws layout (bytes):
//   cbh     @ 0        : ushort[262144] = 524288   (bf16 hi plane of codebook, [k][d])
//   e2f     @ 524288   : float[2048]    = 8192     (np-replica fp32 ||e||^2)
//   Arow    @ 532480   : float[65536]   = 262144   (np-replica fp32 ||x||^2, by score_kernel)
//   idxbuf  @ 794624   : int[65536]     = 262144
//   counts  @ 1056768  : int[2048]      = 8192
//   part    @ 1064960  : double[1536]   = 12288    (rescore 0..1023, fallback 1024..1279)
//   cand_g  @ 1077248  : ushort[65536*16] = 2097152
//   candcnt @ 3174400  : int[65536]     = 262144
// total 3436544 B (~3.44 MB)

// Codebook-only setup: bf16-hi plane + zero histogram (blocks 0..1023),
// np-replica fp32 ||e||^2 (blocks 1024..1031; 8-acc pairwise order, __f*_rn
// blocks FMA contraction so each square rounds like numpy's flat*flat).
__global__ __launch_bounds__(256)
void setup_kernel(const float* __restrict__ cb, ushort* __restrict__ cbh,
                  float* __restrict__ e2f, int* __restrict__ counts) {
  const int bid = blockIdx.x, tid = threadIdx.x;
  if (bid < 1024) {
    const int g = bid * 256 + tid;                // 262144 codebook elems
    const unsigned u = __float_as_uint(cb[g]);
    cbh[g] = (ushort)((u + 0x7FFFu + ((u >> 16) & 1u)) >> 16);  // RNE bf16
    if (g < Kk) counts[g] = 0;
  } else {
    const int k = (bid - 1024) * 256 + tid;       // 2048 codes
    const float* p = cb + (size_t)k * Dd;
    float r[8];
    #pragma unroll
    for (int j = 0; j < 8; ++j) r[j] = __fmul_rn(p[j], p[j]);
    for (int i = 1; i < 16; ++i) {
      #pragma unroll
      for (int j = 0; j < 8; ++j) {
        const float v = p[8 * i + j];
        r[j] = __fadd_rn(r[j], __fmul_rn(v, v));
      }
    }
    e2f[k] = __fadd_rn(__fadd_rn(__fadd_rn(r[0], r[1]), __fadd_rn(r[2], r[3])),
                       __fadd_rn(__fadd_rn(r[4], r[5]), __fadd_rn(r[6], r[7])));
  }
}

// Single-sweep bf16 MFMA scoring, per-thread top-3 packed keys, DMA staging.
// key = (mono(score) & ~0x7FF) | k  — u32-monotone in score, ties -> low k.
// 64 rows/block, 32 chunks of 64 codes; wave tile 32x32 (4x 16x16x32 MFMA).
__global__ __launch_bounds__(256, 3)
void score_kernel(const float* __restrict__ z, const ushort* __restrict__ cbh,
                  const float* __restrict__ e2f, float* __restrict__ Arow,
                  ushort* __restrict__ cand_g, int* __restrict__ candcnt) {
  __shared__ char smem[32768];
  __shared__ float marg[64];
  __shared__ unsigned seedk[64];
  float* zs = (float*)smem;                      // [128][64] fp32 (staging phase)
  ushort* eh = (ushort*)smem;                    // [8192] swizzled (sweep phase)
  unsigned* sred = (unsigned*)(smem + 16384);    // [64][32] (post-sweep)
  int* cnt = (int*)(smem + 24576);               // [64]
  ushort* candL = (ushort*)(smem + 24832);       // [64][16]
  const int tid = threadIdx.x;
  const int n0 = blockIdx.x * 64;                // 1024 blocks
  const int bb = n0 >> 10, t0 = n0 & 1023;
  const float* zb = z + (size_t)bb * DT + t0;
  const int lane = tid & 63, wv = tid >> 6;
  // ---- DMA-stage z fp32 into zs[d][row]: lane covers d=lane>>4, rows (lane&15)*4.. ----
  {
    #pragma unroll
    for (int it = 0; it < 8; ++it) {
      const int d0 = it * 16 + wv * 4;           // 4 d-values per wave-issue
      const int d = d0 + (lane >> 4);
      const int row = (lane & 15) * 4;
      dma16(zb + (size_t)d * Tt + row, zs + (size_t)d0 * 64);
    }
  }
  __syncthreads();
  const int col = lane & 15, quad = lane >> 4;
  const int R0 = (wv >> 1) * 32, C0 = (wv & 1) * 32;
  // ---- A-frag preload (bf16 RNE) into registers ----
  short8 ahf[2][4];
  #pragma unroll
  for (int rt = 0; rt < 2; ++rt) {
    const int row = R0 + rt * 16 + col;
    #pragma unroll
    for (int ks = 0; ks < 4; ++ks) {
      const int d0 = (ks * 4 + quad) * 8;
      short8 t;
      #pragma unroll
      for (int j = 0; j < 8; ++j) {
        const unsigned u = __float_as_uint(zs[(d0 + j) * 64 + row]);
        t[j] = (short)((u + 0x7FFFu + ((u >> 16) & 1u)) >> 16);
      }
      ahf[rt][ks] = t;
    }
  }
  // ---- Arow (np-replica pairwise fp32) + margin ----
  if (tid < 64) {
    float r8[8];
    #pragma unroll
    for (int j = 0; j < 8; ++j) {
      const float v = zs[j * 64 + tid];
      r8[j] = __fmul_rn(v, v);
    }
    for (int i = 1; i < 16; ++i) {
      #pragma unroll
      for (int j = 0; j < 8; ++j) {
        const float v = zs[(8 * i + j) * 64 + tid];
        r8[j] = __fadd_rn(r8[j], __fmul_rn(v, v));
      }
    }
    const float A = __fadd_rn(__fadd_rn(__fadd_rn(r8[0], r8[1]), __fadd_rn(r8[2], r8[3])),
                              __fadd_rn(__fadd_rn(r8[4], r8[5]), __fadd_rn(r8[6], r8[7])));
    Arow[n0 + tid] = A;
    marg[tid] = 8.7e-5f * sqrtf(A) + 1.5e-4f;   // R5-validated + key-trunc slack
  }
  unsigned t1[8], t2[8], t3[8];
  #pragma unroll
  for (int sl = 0; sl < 8; ++sl) { t1[sl] = 0xFFFFFFFFu; t2[sl] = 0xFFFFFFFFu; t3[sl] = 0xFFFFFFFFu; }
  const float4v vzero = {0.f, 0.f, 0.f, 0.f};
  // ---- sweep: DMA-staged eh chunks, top-3 keys ----
  for (int ch = 0; ch < 32; ++ch) {
    __syncthreads();                             // prev chunk readers done / zs dead
    #pragma unroll
    for (int sw = 0; sw < 4; ++sw) {             // 1024 slots of 16B, lane-linear dest
      const int s = sw * 256 + tid;
      const int c = s >> 4, kb = (s & 15) ^ (c & 15);
      dma16(cbh + (((size_t)(ch * 64 + c)) << 7) + (kb << 3),
            eh + (size_t)(sw * 256 + wv * 64) * 8);
    }
    __syncthreads();                             // DMA drained (vmcnt before barrier)
    float4v acc[2][2];
    #pragma unroll
    for (int rt = 0; rt < 2; ++rt)
      #pragma unroll
      for (int ct = 0; ct < 2; ++ct) acc[rt][ct] = vzero;
    #pragma unroll
    for (int ks = 0; ks < 4; ++ks) {
      const int kb = ks * 4 + quad;
      short8 bh[2];
      #pragma unroll
      for (int ct = 0; ct < 2; ++ct)
        bh[ct] = *(const short8*)&eh[((C0 + ct * 16 + col) << 7) + ((kb ^ col) << 3)];
      #pragma unroll
      for (int rt = 0; rt < 2; ++rt)
        #pragma unroll
        for (int ct = 0; ct < 2; ++ct)
          acc[rt][ct] = __builtin_amdgcn_mfma_f32_16x16x32_bf16(ahf[rt][ks], bh[ct], acc[rt][ct], 0, 0, 0);
    }
    const int c0g = ch * 64;
    #pragma unroll
    for (int ct = 0; ct < 2; ++ct) {
      const int kg0 = c0g + C0 + ct * 16 + col;
      const float e2v = e2f[kg0];
      #pragma unroll
      for (int rt = 0; rt < 2; ++rt)
        #pragma unroll
        for (int r = 0; r < 4; ++r) {
          const float s = __builtin_fmaf(-2.0f, acc[rt][ct][r], e2v);
          const unsigned u = __float_as_uint(s);
          const unsigned mono = u ^ ((unsigned)(((int)u) >> 31) | 0x80000000u);
          const unsigned key = (mono & 0xFFFFF800u) | (unsigned)kg0;
          const int sl = rt * 4 + r;
          const unsigned m1 = umax_(t1[sl], key); t1[sl] = umin_(t1[sl], key);
          const unsigned m2 = umax_(t2[sl], m1);  t2[sl] = umin_(t2[sl], m1);
          t3[sl] = umin_(t3[sl], m2);
        }
    }
  }
  __syncthreads();
  // ---- row-global min (u32 keys) -> threshold key ----
  #pragma unroll
  for (int rt = 0; rt < 2; ++rt)
    #pragma unroll
    for (int r = 0; r < 4; ++r)
      sred[(R0 + rt * 16 + quad * 4 + r) * 32 + (wv & 1) * 16 + col] = t1[rt * 4 + r];
  if (tid < 64) cnt[tid] = 0;
  __syncthreads();
  if (tid < 64) {
    unsigned m = sred[tid * 32];
    for (int j = 1; j < 32; ++j) m = umin_(m, sred[tid * 32 + j]);
    const unsigned mt = m & 0xFFFFF800u;                 // trunc-down (conservative)
    const unsigned uu = (mt & 0x80000000u) ? (mt ^ 0x80000000u) : ~mt;
    const float tf = __uint_as_float(uu) + marg[tid];
    const unsigned u2 = __float_as_uint(tf);
    const unsigned mono2 = u2 ^ ((unsigned)(((int)u2) >> 31) | 0x80000000u);
    seedk[tid] = mono2 | 0x7FFu;                         // inclusive in trunc domain
  }
  __syncthreads();
  // ---- append qualifying candidates; flag unbounded threads ----
  #pragma unroll
  for (int rt = 0; rt < 2; ++rt)
    #pragma unroll
    for (int r = 0; r < 4; ++r) {
      const int sl = rt * 4 + r;
      const int row = R0 + rt * 16 + quad * 4 + r;
      const unsigned th = seedk[row];
      if (t1[sl] <= th) {
        const int pos = atomicAdd(&cnt[row], 1);
        if (pos < 16) candL[row * 16 + pos] = (ushort)(t1[sl] & 0x7FFu);
        if (t2[sl] <= th) {
          const int pos2 = atomicAdd(&cnt[row], 1);
          if (pos2 < 16) candL[row * 16 + pos2] = (ushort)(t2[sl] & 0x7FFu);
          if (t3[sl] <= th) atomicAdd(&cnt[row], 64);   // 4th qualifier unbounded -> fallback
        }
      }
    }
  __syncthreads();
  if (tid < 64) {
    const int n = n0 + tid;
    candcnt[n] = cnt[tid];
    uint4* dst = (uint4*)(cand_g + (size_t)n * 16);
    const uint4* src = (const uint4*)(candL + tid * 16);
    dst[0] = src[0];
    dst[1] = src[1];
  }
}

// Exact np-replica rescore: 4 threads/row (f64 dim-quarter partials, width-4
// shuffle combine), fl32-quantized decision (R2-verified) + f64 loss partials.
__global__ __launch_bounds__(256)
void rescore_kernel(const float* __restrict__ z, const float* __restrict__ cb,
                    const float* __restrict__ e2f, const float* __restrict__ Arow,
                    const ushort* __restrict__ cand_g, const int* __restrict__ candcnt,
                    int* __restrict__ idxbuf, int* __restrict__ counts,
                    float* __restrict__ out_idx, double* __restrict__ part) {
  const int tid = threadIdx.x;
  const int r = tid >> 2;                         // row-in-block 0..63
  const int q = tid & 3;                          // dim quarter
  const int n = blockIdx.x * 64 + r;              // 1024 blocks
  const int c = candcnt[n];
  double sq = 0.0;
  if (c >= 1 && c <= 16) {                        // fallback handles the rest
    const int b = n >> 10, t = n & 1023;
    const float* zb = z + (size_t)b * DT + t;
    double xz[32];
    #pragma unroll
    for (int j = 0; j < 32; ++j) xz[j] = (double)zb[(size_t)(q * 32 + j) * Tt];
    const float A = Arow[n];
    float best = 1e30f;
    int bk = Kk;
    for (int j = 0; j < c; ++j) {
      const int k = cand_g[(size_t)n * 16 + j];
      const float* e = cb + (size_t)k * Dd + q * 32;
      double acc = 0.0;
      #pragma unroll
      for (int d4 = 0; d4 < 8; ++d4) {
        const float4 ev = *(const float4*)(e + d4 * 4);
        acc += xz[d4 * 4 + 0] * (double)ev.x;
        acc += xz[d4 * 4 + 1] * (double)ev.y;
        acc += xz[d4 * 4 + 2] * (double)ev.z;
        acc += xz[d4 * 4 + 3] * (double)ev.w;
      }
      acc += __shfl_down(acc, 1, 4);
      acc += __shfl_down(acc, 2, 4);
      if (q == 0) {
        const float m32 = (float)acc;
        const float Dq = __fadd_rn(__fsub_rn(A, __fmul_rn(2.0f, m32)), e2f[k]);
        if (Dq < best || (Dq == best && k < bk)) { best = Dq; bk = k; }
      }
    }
    bk = __shfl(bk, 0, 4);
    if (q == 0) {
      idxbuf[n] = bk;
      out_idx[n] = (float)bk;
      atomicAdd(&counts[bk], 1);
    }
    const float* ew = cb + (size_t)bk * Dd + q * 32;   // winner loss partial
    #pragma unroll
    for (int jj = 0; jj < 32; ++jj) {
      const double dif = xz[jj] - (double)ew[jj];
      sq += dif * dif;
    }
  }
  #pragma unroll
  for (int o = 32; o > 0; o >>= 1) sq += __shfl_down(sq, o, 64);
  __shared__ double w4[4];
  if ((tid & 63) == 0) w4[tid >> 6] = sq;
  __syncthreads();
  if (tid == 0) part[blockIdx.x] = w4[0] + w4[1] + w4[2] + w4[3];
}

// Fallback: full exact scan for flagged/overflowed rows (expected: ~20 rows).
__global__ __launch_bounds__(256)
void fallback_kernel(const float* __restrict__ z, const float* __restrict__ cb,
                     const float* __restrict__ e2f, const float* __restrict__ Arow,
                     const int* __restrict__ candcnt, int* __restrict__ idxbuf,
                     int* __restrict__ counts, float* __restrict__ out_idx,
                     double* __restrict__ part) {
  __shared__ int flags[256];
  __shared__ int nf;
  __shared__ float xrow[128];
  __shared__ float rs[256];
  __shared__ int rk[256];
  const int tid = threadIdx.x;
  const int nb = blockIdx.x * 256;                // 256 blocks
  if (tid == 0) { nf = 0; part[1024 + blockIdx.x] = 0.0; }
  __syncthreads();
  const int c = candcnt[nb + tid];
  const int bad = (c < 1 || c > 16) ? 1 : 0;
  flags[tid] = bad;
  if (bad) atomicAdd(&nf, 1);
  __syncthreads();
  if (nf == 0) return;                            // fast path
  double bsum = 0.0;
  for (int rr = 0; rr < 256; ++rr) {
    if (!flags[rr]) continue;                     // block-uniform
    const int n = nb + rr;
    const int b = n >> 10, t = n & 1023;
    if (tid < 128) xrow[tid] = z[(size_t)b * DT + (size_t)tid * Tt + t];
    __syncthreads();
    const float A = Arow[n];
    float best = 1e30f;
    int bk = Kk;
    for (int kk = tid * 8; kk < tid * 8 + 8; ++kk) {
      const float* e = cb + (size_t)kk * Dd;
      double acc = 0.0;
      for (int d = 0; d < 128; d += 4) {
        const float4 ev = *(const float4*)(e + d);
        acc += (double)xrow[d + 0] * (double)ev.x;
        acc += (double)xrow[d + 1] * (double)ev.y;
        acc += (double)xrow[d + 2] * (double)ev.z;
        acc += (double)xrow[d + 3] * (double)ev.w;
      }
      const float m32 = (float)acc;
      const float Dq = __fadd_rn(__fsub_rn(A, __fmul_rn(2.0f, m32)), e2f[kk]);
      if (Dq < best || (Dq == best && kk < bk)) { best = Dq; bk = kk; }
    }
    rs[tid] = best;
    rk[tid] = bk;
    __syncthreads();
    for (int o = 128; o > 0; o >>= 1) {
      if (tid < o) {
        if (rs[tid + o] < rs[tid] || (rs[tid + o] == rs[tid] && rk[tid + o] < rk[tid])) {
          rs[tid] = rs[tid + o];
          rk[tid] = rk[tid + o];
        }
      }
      __syncthreads();
    }
    if (tid == 0) {
      const int w = rk[0];
      idxbuf[n] = w;
      out_idx[n] = (float)w;
      atomicAdd(&counts[w], 1);
      const float* ew = cb + (size_t)w * Dd;
      for (int d = 0; d < 128; ++d) {
        const double dif = (double)xrow[d] - (double)ew[d];
        bsum += dif * dif;
      }
    }
    __syncthreads();
  }
  if (tid == 0) part[1024 + blockIdx.x] = bsum;
}

// Gather z_q into (B,D,T) layout (R5 measured-good version).
__global__ __launch_bounds__(256)
void gather_kernel(const float* __restrict__ cb, const int* __restrict__ idxbuf,
                   float* __restrict__ out0) {
  const int tid = threadIdx.x;
  const size_t o0 = ((size_t)blockIdx.x * 256 + tid) * 8;  // 4096 blocks
  const int b = (int)(o0 >> 17);
  const int dt = (int)(o0 & (size_t)(DT - 1));
  const int d = dt >> 10;
  const int t = dt & 1023;
  const int n = (b << 10) + t;
  float q[8];
  #pragma unroll
  for (int j = 0; j < 8; ++j) q[j] = cb[(size_t)idxbuf[n + j] * Dd + d];
  *(float4*)(out0 + o0)     = make_float4(q[0], q[1], q[2], q[3]);
  *(float4*)(out0 + o0 + 4) = make_float4(q[4], q[5], q[6], q[7]);
}

__global__ __launch_bounds__(256)
void finalize_kernel(const int* __restrict__ counts, const double* __restrict__ part,
                     float* __restrict__ out) {
  const int tid = threadIdx.x;
  __shared__ double red[256];
  double s = 0.0;
  for (int i = tid; i < 1280; i += 256) s += part[i];
  red[tid] = s;
  __syncthreads();
  for (int o = 128; o > 0; o >>= 1) {
    if (tid < o) red[tid] += red[tid + o];
    __syncthreads();
  }
  const double loss = red[0];
  __syncthreads();
  double e = 0.0;
  for (int k = tid; k < 2048; k += 256) {
    const double p = (double)counts[k] / 65536.0;
    e += p * log(p + 1e-10);
  }
  red[tid] = e;
  __syncthreads();
  for (int o = 128; o > 0; o >>= 1) {
    if (tid < o) red[tid] += red[tid + o];
    __syncthreads();
  }
  if (tid == 0) {
    out[8388608] = (float)(0.25 * loss / 8388608.0);
    out[8388609] = (float)exp(-red[0]);
  }
}

extern "C" void kernel_launch(void* const* d_in, const int* in_sizes, int n_in,
                              void* d_out, int out_size, void* d_ws, size_t ws_size,
                              hipStream_t stream) {
  const float* z = (const float*)d_in[0];      // (B, D, T) fp32
  const float* cb = (const float*)d_in[1];     // (K, D) fp32
  float* out = (float*)d_out;                  // [z_q (8388608) | loss | perp | idx (65536)]
  char* ws = (char*)d_ws;
  ushort* cbh    = (ushort*)ws;
  float* e2f     = (float*)(ws + 524288);
  float* Arow    = (float*)(ws + 532480);
  int* idxbuf    = (int*)(ws + 794624);
  int* counts    = (int*)(ws + 1056768);
  double* part   = (double*)(ws + 1064960);
  ushort* cand_g = (ushort*)(ws + 1077248);
  int* candcnt   = (int*)(ws + 3174400);

  hipLaunchKernelGGL(setup_kernel,    dim3(1032), dim3(256), 0, stream, cb, cbh, e2f, counts);
  hipLaunchKernelGGL(score_kernel,    dim3(1024), dim3(256), 0, stream, z, cbh, e2f, Arow,
                     cand_g, candcnt);
  hipLaunchKernelGGL(rescore_kernel,  dim3(1024), dim3(256), 0, stream, z, cb, e2f, Arow,
                     cand_g, candcnt, idxbuf, counts, out + 8388610, part);
  hipLaunchKernelGGL(fallback_kernel, dim3(256),  dim3(256), 0, stream, z, cb, e2f, Arow,
                     candcnt, idxbuf, counts, out + 8388610, part);
  hipLaunchKernelGGL(gather_kernel,   dim3(4096), dim3(256), 0, stream, cb, idxbuf, out);
  hipLaunchKernelGGL(finalize_kernel, dim3(1),    dim3(256), 0, stream, counts, part, out);
}